// Round 1
// baseline (4920.148 us; speedup 1.0000x reference)
//
#include <hip/hip_runtime.h>
#include <cstddef>

#define T_STEPS 512
#define ROWS    65536      // B*T = 128*512
#define XW      544        // full feature width

__device__ __forceinline__ float fast_sigmoid(float x) {
    return 1.f / (1.f + __expf(-x));
}
__device__ __forceinline__ float fast_tanh(float x) {
    x = fminf(fmaxf(x, -15.f), 15.f);
    float e = __expf(2.f * x);
    return (e - 1.f) / (e + 1.f);
}

// Generic fp32 tiled GEMM: C[row, ccol+n] (= or +=) act( A[grow, acol+k] * W[n][k] + bias[n] )
// W element [n][k] lives at W[n*ldw + k*kstride + koff]  (kstride=2/koff=tap for conv weights)
// gdil > 0: A row gather  grow = (b, max(t-gdil, 0))  -- causal conv "past" tap
__global__ __launch_bounds__(256) void gemm_kernel(
    const float* __restrict__ A, int lda, int acol,
    const float* __restrict__ W, int ldw, int kstride, int koff,
    const float* __restrict__ bias,
    float* __restrict__ C, int ldc, int ccol,
    int N, int K, int gdil, int accum, int act)
{
    __shared__ __align__(16) float As[64][36];
    __shared__ __align__(16) float Ws[64][36];

    const int tid = threadIdx.x;
    const int m0 = blockIdx.x * 64;
    const int n0 = blockIdx.y * 64;
    const int r = tid >> 6;     // 0..3  (uniform per wave)
    const int c = tid & 63;     // lane

    float acc[16];
#pragma unroll
    for (int i = 0; i < 16; ++i) acc[i] = 0.f;

    const int nchunks = (K + 31) >> 5;
    for (int kc = 0; kc < nchunks; ++kc) {
        const int k0 = kc << 5;
        // stage A tile 64x32
#pragma unroll
        for (int it = 0; it < 8; ++it) {
            int flat = tid + it * 256;
            int rr = flat >> 5, kk = flat & 31;
            int row = m0 + rr;
            if (gdil > 0) {
                int t = row & (T_STEPS - 1);
                int tp = t - gdil; if (tp < 0) tp = 0;
                row = (row & ~(T_STEPS - 1)) | tp;
            }
            float v = 0.f;
            if (k0 + kk < K) v = A[(size_t)row * lda + acol + k0 + kk];
            As[rr][kk] = v;
        }
        // stage W tile 64x32
#pragma unroll
        for (int it = 0; it < 8; ++it) {
            int flat = tid + it * 256;
            int nn = flat >> 5, kk = flat & 31;
            float v = 0.f;
            if (n0 + nn < N && k0 + kk < K)
                v = W[(size_t)(n0 + nn) * ldw + (size_t)(k0 + kk) * kstride + koff];
            Ws[nn][kk] = v;
        }
        __syncthreads();
#pragma unroll
        for (int k4 = 0; k4 < 8; ++k4) {
            float4 wv = *(const float4*)&Ws[c][k4 * 4];
#pragma unroll
            for (int i = 0; i < 16; ++i) {
                float4 av = *(const float4*)&As[r * 16 + i][k4 * 4];
                acc[i] += av.x * wv.x + av.y * wv.y + av.z * wv.z + av.w * wv.w;
            }
        }
        __syncthreads();
    }

    const int n = n0 + c;
    if (n < N) {
        float b = bias ? bias[n] : 0.f;
#pragma unroll
        for (int i = 0; i < 16; ++i) {
            size_t row = m0 + r * 16 + i;
            float v = acc[i] + b;
            size_t idx = row * ldc + ccol + n;
            if (accum) v += C[idx];
            if (act) v = fast_tanh(v);
            C[idx] = v;
        }
    }
}

// GRU scan: 1 block per batch, 192 threads (one per gate-row of whh).
// whh row kept in VGPRs; h broadcast via LDS float4 reads. Gate order r,z,n.
__global__ __launch_bounds__(192) void gru_scan_kernel(
    const float* __restrict__ xp,    // [B*T, 192] precomputed x@wih^T + bih
    const float* __restrict__ whh,   // [192, 64]
    const float* __restrict__ bhh,   // [192]
    float* __restrict__ xout, int ldx, int ccol)
{
    __shared__ __align__(16) float h[64];
    __shared__ float pre[192];
    __shared__ float xn[64];

    const int b = blockIdx.x;
    const int g = threadIdx.x;

    float w[64];
#pragma unroll
    for (int k = 0; k < 64; ++k) w[k] = whh[g * 64 + k];
    const float bh = bhh[g];

    float hreg = 0.f;
    if (g < 64) h[g] = 0.f;
    __syncthreads();

    const float* xpb = xp + (size_t)b * T_STEPS * 192;
    float xt = xpb[g];

    for (int t = 0; t < T_STEPS; ++t) {
        float xnext = (t < T_STEPS - 1) ? xpb[(size_t)(t + 1) * 192 + g] : 0.f;

        // gh_g = dot(whh[g], h) + bhh[g]
        float a0 = 0.f, a1 = 0.f, a2 = 0.f, a3 = 0.f;
        const float4* h4 = (const float4*)h;
#pragma unroll
        for (int q = 0; q < 16; ++q) {
            float4 hv = h4[q];
            a0 += w[4 * q + 0] * hv.x;
            a1 += w[4 * q + 1] * hv.y;
            a2 += w[4 * q + 2] * hv.z;
            a3 += w[4 * q + 3] * hv.w;
        }
        float gh = (a0 + a1) + (a2 + a3) + bh;

        if (g < 128) {
            pre[g] = xt + gh;          // r, z gates: x-part + h-part
        } else {
            pre[g] = gh;               // n gate: h-part only (gets r* later)
            xn[g - 128] = xt;          // n gate x-part
        }
        __syncthreads();

        if (g < 64) {
            float rg = fast_sigmoid(pre[g]);
            float zg = fast_sigmoid(pre[64 + g]);
            float ng = fast_tanh(xn[g] + rg * pre[128 + g]);
            hreg = (1.f - zg) * ng + zg * hreg;
            h[g] = hreg;
            xout[((size_t)b * T_STEPS + t) * ldx + ccol + g] = hreg;
        }
        __syncthreads();
        xt = xnext;
    }
}

extern "C" void kernel_launch(void* const* d_in, const int* in_sizes, int n_in,
                              void* d_out, int out_size, void* d_ws, size_t ws_size,
                              hipStream_t stream) {
    const float* features = (const float*)d_in[0];
    const float* d1_w = (const float*)d_in[1];
    const float* d1_b = (const float*)d_in[2];
    const float* z_w  = (const float*)d_in[33];
    const float* z_b  = (const float*)d_in[34];
    const float* s1_w = (const float*)d_in[35];
    const float* s1_b = (const float*)d_in[36];
    const float* s2_w = (const float*)d_in[37];
    const float* s2_b = (const float*)d_in[38];

    float* x  = (float*)d_ws;                       // [65536, 544]
    float* xp = x + (size_t)ROWS * XW;              // [65536, 192]
    float* s1buf = xp;                              // reuse after GRUs done
    float* zout = (float*)d_out;                    // [65536, 80]
    float* sout = zout + (size_t)ROWS * 80;         // [65536, 24]

    dim3 blk(256);

    // d1: x[:, 0:64] = tanh(features @ d1_w^T + d1_b)
    gemm_kernel<<<dim3(ROWS / 64, 1), blk, 0, stream>>>(
        features, 40, 0, d1_w, 40, 1, 0, d1_b, x, XW, 0, 64, 40, 0, 0, 1);

    const int gru_in[5] = {64, 160, 256, 352, 448};
    const int dil[5]    = {1, 2, 2, 2, 2};

    for (int n = 0; n < 5; ++n) {
        const float* wih = (const float*)d_in[3 + n * 4 + 0];
        const float* whh = (const float*)d_in[3 + n * 4 + 1];
        const float* bih = (const float*)d_in[3 + n * 4 + 2];
        const float* bhh = (const float*)d_in[3 + n * 4 + 3];
        const float* cw  = (const float*)d_in[23 + n * 2 + 0];
        const float* cb  = (const float*)d_in[23 + n * 2 + 1];
        const int din = gru_in[n];

        // xp = x[:, 0:din] @ wih^T + bih   (N=192 -> 3 col-blocks)
        gemm_kernel<<<dim3(ROWS / 64, 3), blk, 0, stream>>>(
            x, XW, 0, wih, din, 1, 0, bih, xp, 192, 0, 192, din, 0, 0, 0);

        // sequential GRU scan -> x[:, din:din+64]
        gru_scan_kernel<<<dim3(128), dim3(192), 0, stream>>>(
            xp, whh, bhh, x, XW, din);

        const int dc = din + 64;   // conv input width
        // conv pass 1: past tap (gathered rows), C = A_past @ W0^T
        gemm_kernel<<<dim3(ROWS / 64, 1), blk, 0, stream>>>(
            x, XW, 0, cw, dc * 2, 2, 0, nullptr, x, XW, dc, 32, dc, dil[n], 0, 0);
        // conv pass 2: current tap, C = tanh(C + A @ W1^T + b)
        gemm_kernel<<<dim3(ROWS / 64, 1), blk, 0, stream>>>(
            x, XW, 0, cw, dc * 2, 2, 1, cb, x, XW, dc, 32, dc, 0, 1, 1);
    }

    // z = x @ z_w^T + z_b
    gemm_kernel<<<dim3(ROWS / 64, 2), blk, 0, stream>>>(
        x, XW, 0, z_w, XW, 1, 0, z_b, zout, 80, 0, 80, XW, 0, 0, 0);
    // s1 = tanh(x @ s1_w^T + s1_b)
    gemm_kernel<<<dim3(ROWS / 64, 2), blk, 0, stream>>>(
        x, XW, 0, s1_w, XW, 1, 0, s1_b, s1buf, 128, 0, 128, XW, 0, 0, 1);
    // states = tanh(s1 @ s2_w^T + s2_b)
    gemm_kernel<<<dim3(ROWS / 64, 1), blk, 0, stream>>>(
        s1buf, 128, 0, s2_w, 128, 1, 0, s2_b, sout, 24, 0, 24, 128, 0, 0, 1);
}

// Round 2
// 1921.012 us; speedup vs baseline: 2.5612x; 2.5612x over previous
//
#include <hip/hip_runtime.h>
#include <hip/hip_bf16.h>
#include <cstddef>

#define T_STEPS 512
#define ROWS    65536      // B*T = 128*512
#define XW      544        // full feature width

typedef __attribute__((ext_vector_type(8))) short bf16x8;
typedef __attribute__((ext_vector_type(4))) float f32x4;

__device__ __forceinline__ float fast_sigmoid(float x) {
    return 1.f / (1.f + __expf(-x));
}
__device__ __forceinline__ float fast_tanh(float x) {
    x = fminf(fmaxf(x, -15.f), 15.f);
    float e = __expf(2.f * x);
    return (e - 1.f) / (e + 1.f);
}

// ---------------------------------------------------------------------------
// Weight prep: fp32 -> bf16, layout [Npad][Kpad] row-major, zero padded.
// mode dc>0: conv weight src [N][dc][2] -> dst[n][k] = k<dc ? w[n][k][0] : w[n][k-dc][1]
// ---------------------------------------------------------------------------
struct WDesc { const float* src; int N; int Npad; int K; int Kpad; int dc; long long off; };
struct WTab  { WDesc e[14]; };

__global__ __launch_bounds__(256) void prep_weights(WTab tab, __hip_bfloat16* __restrict__ dst) {
    WDesc d = tab.e[blockIdx.x];
    const int total = d.Npad * d.Kpad;
    for (int idx = blockIdx.y * blockDim.x + threadIdx.x; idx < total;
         idx += gridDim.y * blockDim.x) {
        int n = idx / d.Kpad;
        int k = idx - n * d.Kpad;
        float v = 0.f;
        if (n < d.N && k < d.K) {
            if (d.dc > 0)
                v = (k < d.dc) ? d.src[(n * d.dc + k) * 2]
                               : d.src[(n * d.dc + (k - d.dc)) * 2 + 1];
            else
                v = d.src[(size_t)n * d.K + k];
        }
        dst[d.off + idx] = __float2bfloat16(v);
    }
}

// features [ROWS][40] fp32 -> fbf [ROWS][64] bf16 (zero padded)
__global__ __launch_bounds__(256) void prep_features(const float* __restrict__ f,
                                                     __hip_bfloat16* __restrict__ o) {
    for (int idx = blockIdx.x * blockDim.x + threadIdx.x; idx < ROWS * 64;
         idx += gridDim.x * blockDim.x) {
        int r = idx >> 6, c = idx & 63;
        o[idx] = __float2bfloat16(c < 40 ? f[(size_t)r * 40 + c] : 0.f);
    }
}

// ---------------------------------------------------------------------------
// bf16 MFMA GEMM: C[row, ccol+n] = act( sum_k A[grow(row), k] * W[n][k] + bias[n] )
//  - tile 128x64, BK=32, 256 threads (4 waves; wave w: rows w*32..w*32+31, all 64 cols)
//  - A,W staged via global_load_lds(16B) with pre-swizzled source (granule XOR (row>>1)&3)
//  - dc>0: conv mode, K=2*dc; k<dc reads past row (t-gdil clamped), else current row
//  - N may be < 64*gridDim.y (writes guarded); W must be padded to Npad x Kpad with zeros
// ---------------------------------------------------------------------------
__global__ __launch_bounds__(256) void mm_bf16(
    const __hip_bfloat16* __restrict__ A, int lda,
    const __hip_bfloat16* __restrict__ W, int ldw,
    const float* __restrict__ bias,
    void* __restrict__ Cout, int ldc, int ccol, int N, int K,
    int dc, int gdil, int act, int outbf)
{
    __shared__ __align__(16) unsigned short As[128 * 32];
    __shared__ __align__(16) unsigned short Ws[64 * 32];

    const int tid  = threadIdx.x;
    const int w    = tid >> 6;
    const int lane = tid & 63;
    const int m0   = blockIdx.x * 128;
    const int n0   = blockIdx.y * 64;

    f32x4 acc[2][4];
#pragma unroll
    for (int m = 0; m < 2; ++m)
#pragma unroll
        for (int n = 0; n < 4; ++n) acc[m][n] = (f32x4){0.f, 0.f, 0.f, 0.f};

    const int ksteps = K >> 5;
    for (int kc = 0; kc < ksteps; ++kc) {
        const int k0 = kc << 5;
        // stage A tile 128x32 bf16 (8 KB): granule s holds global (row s>>2, kgrp (s&3)^((row>>1)&3))
#pragma unroll
        for (int it = 0; it < 2; ++it) {
            int s  = it * 256 + w * 64 + lane;
            int rl = s >> 2, g = s & 3;
            int gq = g ^ ((rl >> 1) & 3);
            int grow = m0 + rl;
            int gcol = k0 + gq * 8;
            if (dc > 0) {
                if (k0 < dc) {
                    int t = grow & (T_STEPS - 1);
                    int tp = t - gdil; if (tp < 0) tp = 0;
                    grow = (grow & ~(T_STEPS - 1)) | tp;
                } else {
                    gcol -= dc;
                }
            }
            __builtin_amdgcn_global_load_lds(
                (const __attribute__((address_space(1))) void*)(A + (size_t)grow * lda + gcol),
                (__attribute__((address_space(3))) void*)(As + (size_t)(it * 256 + w * 64) * 8),
                16, 0, 0);
        }
        // stage W tile 64x32 bf16 (4 KB)
        {
            int s  = w * 64 + lane;
            int rl = s >> 2, g = s & 3;
            int gq = g ^ ((rl >> 1) & 3);
            __builtin_amdgcn_global_load_lds(
                (const __attribute__((address_space(1))) void*)(W + (size_t)(n0 + rl) * ldw + k0 + gq * 8),
                (__attribute__((address_space(3))) void*)(Ws + (size_t)(w * 64) * 8),
                16, 0, 0);
        }
        __syncthreads();   // drains vmcnt before LDS reads

        const int q = lane >> 4, li = lane & 15;
        bf16x8 af[2], wf[4];
#pragma unroll
        for (int m = 0; m < 2; ++m) {
            int r = w * 32 + m * 16 + li;
            af[m] = *(const bf16x8*)(As + (size_t)(r * 4 + (q ^ ((r >> 1) & 3))) * 8);
        }
#pragma unroll
        for (int n = 0; n < 4; ++n) {
            int r = n * 16 + li;
            wf[n] = *(const bf16x8*)(Ws + (size_t)(r * 4 + (q ^ ((r >> 1) & 3))) * 8);
        }
#pragma unroll
        for (int m = 0; m < 2; ++m)
#pragma unroll
            for (int n = 0; n < 4; ++n)
                acc[m][n] = __builtin_amdgcn_mfma_f32_16x16x32_bf16(af[m], wf[n], acc[m][n], 0, 0, 0);
        __syncthreads();
    }

    // epilogue: C/D layout col=lane&15 (n), row=(lane>>4)*4+reg (m)
    const int q = lane >> 4, li = lane & 15;
#pragma unroll
    for (int m = 0; m < 2; ++m) {
#pragma unroll
        for (int n = 0; n < 4; ++n) {
            int col = n0 + n * 16 + li;
            if (col < N) {
                float bv = bias ? bias[col] : 0.f;
#pragma unroll
                for (int j = 0; j < 4; ++j) {
                    int row = m0 + w * 32 + m * 16 + q * 4 + j;
                    float v = acc[m][n][j] + bv;
                    if (act) v = fast_tanh(v);
                    if (outbf)
                        ((__hip_bfloat16*)Cout)[(size_t)row * ldc + ccol + col] = __float2bfloat16(v);
                    else
                        ((float*)Cout)[(size_t)row * ldc + ccol + col] = v;
                }
            }
        }
    }
}

// ---------------------------------------------------------------------------
// GRU scan: 1 block per batch, 192 threads (one per gate-row of whh).
// whh row in VGPRs; h broadcast via LDS float4 (same-address broadcast = free).
// Writes h as bf16 into the concat buffer.
// ---------------------------------------------------------------------------
__global__ __launch_bounds__(192) void gru_scan_kernel(
    const float* __restrict__ xp,    // [B*T, 192] = x@wih^T + bih (fp32)
    const float* __restrict__ whh,   // [192, 64]
    const float* __restrict__ bhh,   // [192]
    __hip_bfloat16* __restrict__ xout, int ldx, int ccol)
{
    __shared__ __align__(16) float h[64];
    __shared__ float pre[192];
    __shared__ float xn[64];

    const int b = blockIdx.x;
    const int g = threadIdx.x;

    float w[64];
#pragma unroll
    for (int k = 0; k < 64; ++k) w[k] = whh[g * 64 + k];
    const float bh = bhh[g];

    float hreg = 0.f;
    if (g < 64) h[g] = 0.f;
    __syncthreads();

    const float* xpb = xp + (size_t)b * T_STEPS * 192;
    float xt = xpb[g];

    for (int t = 0; t < T_STEPS; ++t) {
        float xnext = (t < T_STEPS - 1) ? xpb[(size_t)(t + 1) * 192 + g] : 0.f;

        float a0 = 0.f, a1 = 0.f, a2 = 0.f, a3 = 0.f;
        const float4* h4 = (const float4*)h;
#pragma unroll
        for (int qq = 0; qq < 16; ++qq) {
            float4 hv = h4[qq];
            a0 += w[4 * qq + 0] * hv.x;
            a1 += w[4 * qq + 1] * hv.y;
            a2 += w[4 * qq + 2] * hv.z;
            a3 += w[4 * qq + 3] * hv.w;
        }
        float gh = (a0 + a1) + (a2 + a3) + bh;

        if (g < 128) {
            pre[g] = xt + gh;          // r, z gates
        } else {
            pre[g] = gh;               // n gate h-part
            xn[g - 128] = xt;          // n gate x-part
        }
        __syncthreads();

        if (g < 64) {
            float rg = fast_sigmoid(pre[g]);
            float zg = fast_sigmoid(pre[64 + g]);
            float ng = fast_tanh(xn[g] + rg * pre[128 + g]);
            hreg = (1.f - zg) * ng + zg * hreg;
            h[g] = hreg;
            xout[((size_t)b * T_STEPS + t) * ldx + ccol + g] = __float2bfloat16(hreg);
        }
        __syncthreads();
        xt = xnext;
    }
}

extern "C" void kernel_launch(void* const* d_in, const int* in_sizes, int n_in,
                              void* d_out, int out_size, void* d_ws, size_t ws_size,
                              hipStream_t stream) {
    const float* features = (const float*)d_in[0];
    const float* d1_w = (const float*)d_in[1];
    const float* d1_b = (const float*)d_in[2];
    const float* z_w  = (const float*)d_in[33];
    const float* z_b  = (const float*)d_in[34];
    const float* s1_w = (const float*)d_in[35];
    const float* s1_b = (const float*)d_in[36];
    const float* s2_w = (const float*)d_in[37];
    const float* s2_b = (const float*)d_in[38];

    // workspace carve (bytes):
    //   xbf  [ROWS][544] bf16 : 71,303,168
    //   xp   [ROWS][192] f32  : 50,331,648
    //   fbf  [ROWS][64]  bf16 :  8,388,608
    //   s1b  [ROWS][128] bf16 : 16,777,216
    //   wbuf ~602K bf16       :  1,204,224   (total ~148 MB)
    char* ws = (char*)d_ws;
    __hip_bfloat16* xbf  = (__hip_bfloat16*)ws;
    float*          xp   = (float*)(ws + 71303168ull);
    __hip_bfloat16* fbf  = (__hip_bfloat16*)(ws + 121634816ull);
    __hip_bfloat16* s1b  = (__hip_bfloat16*)(ws + 130023424ull);
    __hip_bfloat16* wbuf = (__hip_bfloat16*)(ws + 146800640ull);

    float* zout = (float*)d_out;                 // [ROWS][80]
    float* sout = zout + (size_t)ROWS * 80;      // [ROWS][24]

    const int gru_in[5] = {64, 160, 256, 352, 448};
    const int dil[5]    = {1, 2, 2, 2, 2};

    // weight table
    WTab tab;
    long long off = 0;
    auto add = [&](int i, const float* src, int N, int Npad, int K, int Kpad, int dcv) {
        tab.e[i].src = src; tab.e[i].N = N; tab.e[i].Npad = Npad;
        tab.e[i].K = K; tab.e[i].Kpad = Kpad; tab.e[i].dc = dcv; tab.e[i].off = off;
        off += (long long)Npad * Kpad;
    };
    add(0, d1_w, 64, 64, 40, 64, 0);
    for (int n = 0; n < 5; ++n)
        add(1 + n, (const float*)d_in[3 + n * 4], 192, 192, gru_in[n], gru_in[n], 0);
    for (int n = 0; n < 5; ++n) {
        int dcv = gru_in[n] + 64;
        add(6 + n, (const float*)d_in[23 + n * 2], 32, 64, 2 * dcv, 2 * dcv, dcv);
    }
    add(11, z_w, 80, 128, 544, 544, 0);
    add(12, s1_w, 128, 128, 544, 544, 0);
    add(13, s2_w, 24, 64, 128, 128, 0);

    prep_weights<<<dim3(14, 16), 256, 0, stream>>>(tab, wbuf);
    prep_features<<<2048, 256, 0, stream>>>(features, fbf);

    // d1: xbf[:,0:64] = tanh(fbf @ d1_w^T + b)
    mm_bf16<<<dim3(512, 1), 256, 0, stream>>>(
        fbf, 64, wbuf + tab.e[0].off, 64, d1_b, xbf, XW, 0, 64, 64, 0, 0, 1, 1);

    for (int n = 0; n < 5; ++n) {
        const float* whh = (const float*)d_in[3 + n * 4 + 1];
        const float* bih = (const float*)d_in[3 + n * 4 + 2];
        const float* bhh = (const float*)d_in[3 + n * 4 + 3];
        const float* cb  = (const float*)d_in[23 + n * 2 + 1];
        const int din = gru_in[n];
        const int dcv = din + 64;

        // xp = xbf[:,0:din] @ wih^T + bih   (fp32 out)
        mm_bf16<<<dim3(512, 3), 256, 0, stream>>>(
            xbf, XW, wbuf + tab.e[1 + n].off, din, bih, xp, 192, 0, 192, din, 0, 0, 0, 0);

        // sequential GRU scan -> xbf[:, din:din+64]
        gru_scan_kernel<<<dim3(128), dim3(192), 0, stream>>>(xp, whh, bhh, xbf, XW, din);

        // conv (both taps, one GEMM over K=2*dcv) -> xbf[:, dcv:dcv+32]
        mm_bf16<<<dim3(512, 1), 256, 0, stream>>>(
            xbf, XW, wbuf + tab.e[6 + n].off, 2 * dcv, cb, xbf, XW, dcv, 32, 2 * dcv,
            dcv, dil[n], 1, 1);
    }

    // z = xbf @ z_w^T + z_b (fp32 out)
    mm_bf16<<<dim3(512, 2), 256, 0, stream>>>(
        xbf, XW, wbuf + tab.e[11].off, 544, z_b, zout, 80, 0, 80, 544, 0, 0, 0, 0);
    // s1 = tanh(xbf @ s1_w^T + s1_b) (bf16)
    mm_bf16<<<dim3(512, 2), 256, 0, stream>>>(
        xbf, XW, wbuf + tab.e[12].off, 544, s1_b, s1b, 128, 0, 128, 544, 0, 0, 1, 1);
    // states = tanh(s1b @ s2_w^T + s2_b) (fp32 out)
    mm_bf16<<<dim3(512, 1), 256, 0, stream>>>(
        s1b, 128, wbuf + tab.e[13].off, 128, s2_b, sout, 24, 0, 24, 128, 0, 0, 1, 0);
}